// Round 1
// baseline (1343.065 us; speedup 1.0000x reference)
//
#include <hip/hip_runtime.h>
#include <math.h>

#define TT 512
#define DD 128
#define MM 512
#define EE 512
#define NTAGS 74
#define GH 64
#define LH 256

typedef _Float16 half_t;
typedef _Float16 v2h __attribute__((ext_vector_type(2)));
typedef _Float16 v8h __attribute__((ext_vector_type(8)));
typedef _Float16 v16h __attribute__((ext_vector_type(16)));
typedef int v4i __attribute__((ext_vector_type(4)));

__device__ __forceinline__ float fdot2f(v2h a, v2h b, float c) {
#if __has_builtin(__builtin_amdgcn_fdot2)
    return __builtin_amdgcn_fdot2(a, b, c, false);
#else
    return c + (float)a[0] * (float)b[0] + (float)a[1] * (float)b[1];
#endif
}

__device__ __forceinline__ int sdot4(int a, int b, int c) {
#if __has_builtin(__builtin_amdgcn_sdot4)
    return __builtin_amdgcn_sdot4(a, b, c, false);
#else
    return c + ((a << 24) >> 24) * ((b << 24) >> 24)
             + ((a << 16) >> 24) * ((b << 16) >> 24)
             + ((a << 8) >> 24) * ((b << 8) >> 24)
             + (a >> 24) * (b >> 24);
#endif
}

__device__ __forceinline__ float sigf(float x) { return 1.f / (1.f + __expf(-x)); }
__device__ __forceinline__ float tanhfast(float x) { return 1.f - 2.f / (__expf(2.f * x) + 1.f); }

// LDS-only barrier: orders LDS traffic across the workgroup WITHOUT the
// vmcnt(0) drain that __syncthreads() emits. Global stores (h writeback)
// and prefetch loads stay in flight across it (guide T4; rule 18 fences).
__device__ __forceinline__ void lds_barrier() {
    __builtin_amdgcn_sched_barrier(0);
    asm volatile("s_waitcnt lgkmcnt(0)" ::: "memory");
    __builtin_amdgcn_s_barrier();
    __builtin_amdgcn_sched_barrier(0);
}

// 16 f32 -> v16h (SSA value, 8 VGPRs)
__device__ __forceinline__ v16h load16(const float* p) {
    float4 x0 = ((const float4*)p)[0];
    float4 x1 = ((const float4*)p)[1];
    float4 x2 = ((const float4*)p)[2];
    float4 x3 = ((const float4*)p)[3];
    v16h r;
    r[0] = (half_t)x0.x; r[1] = (half_t)x0.y; r[2] = (half_t)x0.z; r[3] = (half_t)x0.w;
    r[4] = (half_t)x1.x; r[5] = (half_t)x1.y; r[6] = (half_t)x1.z; r[7] = (half_t)x1.w;
    r[8] = (half_t)x2.x; r[9] = (half_t)x2.y; r[10] = (half_t)x2.z; r[11] = (half_t)x2.w;
    r[12] = (half_t)x3.x; r[13] = (half_t)x3.y; r[14] = (half_t)x3.z; r[15] = (half_t)x3.w;
    return r;
}

#define OPAQUE4(a, b, c, d) \
    asm volatile("" : "+v"(a), "+v"(b), "+v"(c), "+v"(d))
#define OPAQUE6(a, b, c, d, e, f) \
    asm volatile("" : "+v"(a), "+v"(b), "+v"(c), "+v"(d), "+v"(e), "+v"(f))

__device__ __forceinline__ void dot16(const v16h& w, const v8h& h0, const v8h& h1,
                                      float& x0, float& x1) {
    x0 = fdot2f(v2h{w[0], w[1]}, v2h{h0[0], h0[1]}, x0);
    x1 = fdot2f(v2h{w[2], w[3]}, v2h{h0[2], h0[3]}, x1);
    x0 = fdot2f(v2h{w[4], w[5]}, v2h{h0[4], h0[5]}, x0);
    x1 = fdot2f(v2h{w[6], w[7]}, v2h{h0[6], h0[7]}, x1);
    x0 = fdot2f(v2h{w[8], w[9]}, v2h{h1[0], h1[1]}, x0);
    x1 = fdot2f(v2h{w[10], w[11]}, v2h{h1[2], h1[3]}, x1);
    x0 = fdot2f(v2h{w[12], w[13]}, v2h{h1[4], h1[5]}, x0);
    x1 = fdot2f(v2h{w[14], w[15]}, v2h{h1[6], h1[7]}, x1);
}

__device__ __forceinline__ int pack4(int b0, int b1, int b2, int b3) {
    return (b0 & 0xff) | ((b1 & 0xff) << 8) | ((b2 & 0xff) << 16) | (b3 << 24);
}

// quantize 16 consecutive f32 weights -> 16 int8 packed in v4i
__device__ __forceinline__ v4i quant16(const float* p, float inv_s) {
    float4 x0 = ((const float4*)p)[0];
    float4 x1 = ((const float4*)p)[1];
    float4 x2 = ((const float4*)p)[2];
    float4 x3 = ((const float4*)p)[3];
    v4i r;
    r.x = pack4(__float2int_rn(x0.x * inv_s), __float2int_rn(x0.y * inv_s),
                __float2int_rn(x0.z * inv_s), __float2int_rn(x0.w * inv_s));
    r.y = pack4(__float2int_rn(x1.x * inv_s), __float2int_rn(x1.y * inv_s),
                __float2int_rn(x1.z * inv_s), __float2int_rn(x1.w * inv_s));
    r.z = pack4(__float2int_rn(x2.x * inv_s), __float2int_rn(x2.y * inv_s),
                __float2int_rn(x2.z * inv_s), __float2int_rn(x2.w * inv_s));
    r.w = pack4(__float2int_rn(x3.x * inv_s), __float2int_rn(x3.y * inv_s),
                __float2int_rn(x3.z * inv_s), __float2int_rn(x3.w * inv_s));
    return r;
}

// ---------------- K1: dots[m] = <memory[m], u> ----------------
__global__ __launch_bounds__(256) void k_dots(const float* __restrict__ mem,
                                              const float* __restrict__ u,
                                              float* __restrict__ dots) {
    int m = blockIdx.x;
    const float4* m4 = (const float4*)(mem + (size_t)m * TT * DD);
    const float4* u4 = (const float4*)u;
    float acc = 0.f;
#pragma unroll 4
    for (int it = 0; it < (TT * DD / 4) / 256; ++it) {
        int i = it * 256 + threadIdx.x;
        float4 a = m4[i], b = u4[i];
        acc += a.x * b.x + a.y * b.y + a.z * b.z + a.w * b.w;
    }
    for (int off = 32; off; off >>= 1) acc += __shfl_down(acc, off, 64);
    __shared__ float red[4];
    int w = threadIdx.x >> 6, l = threadIdx.x & 63;
    if (l == 0) red[w] = acc;
    __syncthreads();
    if (threadIdx.x == 0) dots[m] = red[0] + red[1] + red[2] + red[3];
}

// ---------------- K2: p = softmax(dots) ----------------
__global__ __launch_bounds__(512) void k_softmax_p(const float* __restrict__ dots,
                                                   float* __restrict__ p) {
    int tid = threadIdx.x;
    float v = dots[tid];
    float mx = v;
    for (int off = 32; off; off >>= 1) mx = fmaxf(mx, __shfl_down(mx, off, 64));
    __shared__ float red[8];
    __shared__ float bm, bs;
    int w = tid >> 6, l = tid & 63;
    if (l == 0) red[w] = mx;
    __syncthreads();
    if (tid == 0) {
        float t = red[0];
        for (int i = 1; i < 8; ++i) t = fmaxf(t, red[i]);
        bm = t;
    }
    __syncthreads();
    float e = __expf(v - bm);
    float sm = e;
    for (int off = 32; off; off >>= 1) sm += __shfl_down(sm, off, 64);
    if (l == 0) red[w] = sm;
    __syncthreads();
    if (tid == 0) {
        float t = 0.f;
        for (int i = 0; i < 8; ++i) t += red[i];
        bs = t;
    }
    __syncthreads();
    p[tid] = e / bs;
}

// ---------------- K3: Mbar = sum_m p[m]*memory[m] ----------------
__global__ __launch_bounds__(128) void k_wsum(const float* __restrict__ mem,
                                              const float* __restrict__ p,
                                              float* __restrict__ Mbar) {
    __shared__ float pl[MM];
    for (int i = threadIdx.x; i < MM; i += 128) pl[i] = p[i];
    __syncthreads();
    int i4 = blockIdx.x * 128 + threadIdx.x;
    const float4* m4 = (const float4*)mem;
    float4 acc = {0.f, 0.f, 0.f, 0.f};
#pragma unroll 4
    for (int m = 0; m < MM; ++m) {
        float pm = pl[m];
        float4 a = m4[(size_t)m * (TT * DD / 4) + i4];
        acc.x += pm * a.x; acc.y += pm * a.y; acc.z += pm * a.z; acc.w += pm * a.w;
    }
    ((float4*)Mbar)[i4] = acc;
}

// ---------------- K4: G = Mbar@W1.T + u@W2.T + b_ff ----------------
__global__ __launch_bounds__(128) void k_G(const float* __restrict__ Mbar,
                                           const float* __restrict__ u,
                                           const float* __restrict__ Wff,
                                           const float* __restrict__ bff,
                                           float* __restrict__ G) {
    int t = blockIdx.x, d = threadIdx.x;
    __shared__ __align__(16) float Ml[DD], ul[DD];
    Ml[d] = Mbar[t * DD + d];
    ul[d] = u[t * DD + d];
    __syncthreads();
    const float* wr = Wff + (size_t)d * 2 * DD;
    float a0 = 0.f, a1 = 0.f;
#pragma unroll 4
    for (int k = 0; k < DD; ++k) {
        a0 += Ml[k] * wr[k];
        a1 += ul[k] * wr[DD + k];
    }
    G[t * DD + d] = a0 + a1 + bff[d];
}

// ---------------- K5: GRU input projections ----------------
__global__ __launch_bounds__(384) void k_gru_gi(const float* __restrict__ G,
                                                const float* __restrict__ Wf,
                                                const float* __restrict__ bf,
                                                const float* __restrict__ Wb,
                                                const float* __restrict__ bb,
                                                float* __restrict__ gi) {
    int t = blockIdx.x;
    __shared__ __align__(16) float Gl[DD];
    if (threadIdx.x < DD) Gl[threadIdx.x] = G[t * DD + threadIdx.x];
    __syncthreads();
    int r = threadIdx.x;
    const float* w;
    float b;
    float* o;
    if (r < 192) {
        w = Wf + (size_t)r * DD; b = bf[r]; o = gi + ((size_t)0 * TT + t) * 192 + r;
    } else {
        int rr = r - 192;
        w = Wb + (size_t)rr * DD; b = bb[rr]; o = gi + ((size_t)1 * TT + t) * 192 + rr;
    }
    float a0 = 0.f, a1 = 0.f;
#pragma unroll 4
    for (int k = 0; k < DD; k += 2) {
        a0 += Gl[k] * w[k];
        a1 += Gl[k + 1] * w[k + 1];
    }
    *o = a0 + a1 + b;
}

// ---------------- K6: sequential BiGRU (2 blocks = 2 directions) ----------------
// Per-step sync uses lds_barrier() (lgkmcnt-only): the global h store stays
// in flight, and gi loads are software-pipelined one step ahead so the
// LLC/HBM latency (~500-900 cyc; giG written on other XCDs) is covered by a
// full step instead of stalling at the __syncthreads vmcnt(0) drain.
__global__ __launch_bounds__(256) void k_gru_seq(const float* __restrict__ Whh_f,
                                                 const float* __restrict__ bhh_f,
                                                 const float* __restrict__ Whh_b,
                                                 const float* __restrict__ bhh_b,
                                                 const float* __restrict__ gi,
                                                 float* __restrict__ hbuf) {
    int dir = blockIdx.x;
    int tid = threadIdx.x;
    const float* Whh = dir ? Whh_b : Whh_f;
    const float* bhh = dir ? bhh_b : bhh_f;
    v16h w0 = {}, w1 = {}, w2 = {}, w3 = {};
    float bh = 0.f;
    if (tid < 192) {
        const float* wr = Whh + (size_t)tid * 64;
        w0 = load16(wr);
        w1 = load16(wr + 16);
        w2 = load16(wr + 32);
        w3 = load16(wr + 48);
        bh = bhh[tid];
    }
    OPAQUE4(w0, w1, w2, w3);
    __shared__ __align__(16) half_t hl[64];
    __shared__ float pa[192];
    if (tid < 32) ((v2h*)hl)[tid] = v2h{(half_t)0.f, (half_t)0.f};
    float h = 0.f;
    // prologue: load gi for step 0
    float g_r = 0.f, g_z = 0.f, g_n = 0.f;
    if (tid < 64) {
        int t0 = dir ? (TT - 1) : 0;
        const float* git = gi + ((size_t)dir * TT + t0) * 192;
        g_r = git[tid]; g_z = git[64 + tid]; g_n = git[128 + tid];
    }
    lds_barrier();
    for (int s = 0; s < TT; ++s) {
        int t = dir ? (TT - 1 - s) : s;
        // prefetch gi for step s+1 (clamped; consumed next iteration)
        float p_r = 0.f, p_z = 0.f, p_n = 0.f;
        if (tid < 64) {
            int sn = (s + 1 < TT) ? (s + 1) : s;
            int tn = dir ? (TT - 1 - sn) : sn;
            const float* git = gi + ((size_t)dir * TT + tn) * 192;
            p_r = git[tid]; p_z = git[64 + tid]; p_n = git[128 + tid];
        }
        if (tid < 192) {
            float a0 = bh, a1 = 0.f;
            v8h h0, h1;
            h0 = *(const v8h*)(hl + 0);  h1 = *(const v8h*)(hl + 8);
            dot16(w0, h0, h1, a0, a1);
            h0 = *(const v8h*)(hl + 16); h1 = *(const v8h*)(hl + 24);
            dot16(w1, h0, h1, a0, a1);
            h0 = *(const v8h*)(hl + 32); h1 = *(const v8h*)(hl + 40);
            dot16(w2, h0, h1, a0, a1);
            h0 = *(const v8h*)(hl + 48); h1 = *(const v8h*)(hl + 56);
            dot16(w3, h0, h1, a0, a1);
            pa[tid] = a0 + a1;
        }
        lds_barrier();
        if (tid < 64) {
            float r = sigf(g_r + pa[tid]);
            float z = sigf(g_z + pa[64 + tid]);
            float n = tanhfast(g_n + r * pa[128 + tid]);
            h = (1.f - z) * n + z * h;
            hbuf[t * DD + dir * 64 + tid] = h;   // store left in flight
            hl[tid] = (half_t)h;
        }
        lds_barrier();
        g_r = p_r; g_z = p_z; g_n = p_n;
    }
}

// ---------------- K7: x = embed + (u + h)@W_k.T + b_k ----------------
__global__ __launch_bounds__(512) void k_x(const float* __restrict__ u,
                                           const float* __restrict__ hbuf,
                                           const float* __restrict__ Wk,
                                           const float* __restrict__ bk,
                                           const float* __restrict__ embed,
                                           float* __restrict__ x) {
    int t = blockIdx.x, e = threadIdx.x;
    __shared__ __align__(16) float sl[DD];
    if (e < DD) sl[e] = u[t * DD + e] + hbuf[t * DD + e];
    __syncthreads();
    const float* wr = Wk + (size_t)e * DD;
    float a0 = 0.f, a1 = 0.f;
#pragma unroll 4
    for (int k = 0; k < DD; k += 2) {
        a0 += sl[k] * wr[k];
        a1 += sl[k + 1] * wr[k + 1];
    }
    x[t * EE + e] = embed[t * EE + e] + a0 + a1 + bk[e];
}

// ---------------- K8: LSTM input projections, 8 timesteps per block ----------------
__global__ __launch_bounds__(1024) void k_lstm_gi(const float* __restrict__ x,
                                                  const float* __restrict__ Wf,
                                                  const float* __restrict__ bf,
                                                  const float* __restrict__ Wb,
                                                  const float* __restrict__ bb,
                                                  float* __restrict__ gi) {
    int dir = blockIdx.y;
    int t0 = blockIdx.x * 8;
    __shared__ __align__(16) float xl[8 * EE];
    for (int i = threadIdx.x; i < 8 * EE; i += 1024) xl[i] = x[(size_t)t0 * EE + i];
    __syncthreads();
    int r = threadIdx.x;
    const float* W = dir ? Wb : Wf;
    const float* bi = dir ? bb : bf;
    const float* wr = W + (size_t)r * EE;
    float b = bi[r];
    float acc[8];
#pragma unroll
    for (int uu = 0; uu < 8; ++uu) acc[uu] = b;
    for (int k = 0; k < EE; k += 4) {
        float4 wv = *(const float4*)(wr + k);
#pragma unroll
        for (int uu = 0; uu < 8; ++uu) {
            float4 xv = *(const float4*)(&xl[uu * EE + k]);
            acc[uu] += wv.x * xv.x + wv.y * xv.y + wv.z * xv.z + wv.w * xv.w;
        }
    }
#pragma unroll
    for (int uu = 0; uu < 8; ++uu)
        gi[((size_t)dir * TT + (t0 + uu)) * 1024 + r] = acc[uu];
}

// ---------------- K9: sequential BiLSTM, one WG per direction ----------------
// int8 path: per-row symmetric quant (scale rowmax/127), exact i32 sdot4
// accumulation, one float rescale. 512 threads x 2 rows; cols 0..191 as
// 24 named v4i = 96 VGPRs; cols 192..255 as int8 in LDS (64 KB).
// Per-step sync via lds_barrier() + gi prefetched one step ahead (see K6).
__global__ __launch_bounds__(512) void k_lstm_seq(const float* __restrict__ Whh_f,
                                                  const float* __restrict__ bhh_f,
                                                  const float* __restrict__ Whh_b,
                                                  const float* __restrict__ bhh_b,
                                                  const float* __restrict__ gi,
                                                  float* __restrict__ comb) {
    int dir = blockIdx.x;
    int tid = threadIdx.x;
    int u = tid & 255;
    int hi = tid >> 8;               // 0 -> rows (i,g); 1 -> rows (f,o)
    int r0 = hi * 256 + u;           // gate i or f
    int r1 = 512 + hi * 256 + u;     // gate g or o
    const float* Whh = dir ? Whh_b : Whh_f;
    const float* bhh = dir ? bhh_b : bhh_f;

    __shared__ __align__(16) int wsl[4][1024][4];  // [chunk][row][16 int8] = 64 KB
    __shared__ __align__(16) int hq[64];           // 256 int8 = current h
    __shared__ float pa[1024];

    const float* s0 = Whh + (size_t)r0 * 256;
    const float* s1 = Whh + (size_t)r1 * 256;
    // per-row scales
    float mx0 = 0.f, mx1 = 0.f;
    for (int k = 0; k < 256; k += 4) {
        float4 a = *(const float4*)(s0 + k);
        float4 b = *(const float4*)(s1 + k);
        mx0 = fmaxf(mx0, fmaxf(fmaxf(fabsf(a.x), fabsf(a.y)), fmaxf(fabsf(a.z), fabsf(a.w))));
        mx1 = fmaxf(mx1, fmaxf(fmaxf(fabsf(b.x), fabsf(b.y)), fmaxf(fabsf(b.z), fabsf(b.w))));
    }
    float inv0 = 127.f / mx0, inv1 = 127.f / mx1;
    float fs0 = mx0 / 16129.f, fs1 = mx1 / 16129.f;  // mx/(127*127)

    // LDS weight slice: cols 192..255 of own rows.
#pragma unroll
    for (int cc = 0; cc < 4; ++cc) {
        *(v4i*)&wsl[cc][r0][0] = quant16(s0 + 192 + 16 * cc, inv0);
        *(v4i*)&wsl[cc][r1][0] = quant16(s1 + 192 + 16 * cc, inv1);
    }
    // Register weights: cols 0..191 of both rows.
    v4i wa0 = quant16(s0, inv0),        wa1 = quant16(s0 + 16, inv0),
        wa2 = quant16(s0 + 32, inv0),   wa3 = quant16(s0 + 48, inv0),
        wa4 = quant16(s0 + 64, inv0),   wa5 = quant16(s0 + 80, inv0),
        wa6 = quant16(s0 + 96, inv0),   wa7 = quant16(s0 + 112, inv0),
        wa8 = quant16(s0 + 128, inv0),  wa9 = quant16(s0 + 144, inv0),
        wa10 = quant16(s0 + 160, inv0), wa11 = quant16(s0 + 176, inv0);
    v4i wb0 = quant16(s1, inv1),        wb1 = quant16(s1 + 16, inv1),
        wb2 = quant16(s1 + 32, inv1),   wb3 = quant16(s1 + 48, inv1),
        wb4 = quant16(s1 + 64, inv1),   wb5 = quant16(s1 + 80, inv1),
        wb6 = quant16(s1 + 96, inv1),   wb7 = quant16(s1 + 112, inv1),
        wb8 = quant16(s1 + 128, inv1),  wb9 = quant16(s1 + 144, inv1),
        wb10 = quant16(s1 + 160, inv1), wb11 = quant16(s1 + 176, inv1);
    OPAQUE6(wa0, wa1, wa2, wa3, wa4, wa5);
    OPAQUE6(wa6, wa7, wa8, wa9, wa10, wa11);
    OPAQUE6(wb0, wb1, wb2, wb3, wb4, wb5);
    OPAQUE6(wb6, wb7, wb8, wb9, wb10, wb11);
    float bh0 = bhh[r0], bh1 = bhh[r1];
    if (tid < 64) hq[tid] = 0;
    float c_state = 0.f;
    // prologue: load gi for step 0
    int tfirst = dir ? (TT - 1) : 0;
    float g0v = gi[((size_t)dir * TT + tfirst) * 1024 + r0];
    float g1v = gi[((size_t)dir * TT + tfirst) * 1024 + r1];
    lds_barrier();

    for (int s = 0; s < TT; ++s) {
        int t = dir ? (TT - 1 - s) : s;
        // prefetch gi for step s+1 (clamped; consumed next iteration)
        int sn = (s + 1 < TT) ? (s + 1) : s;
        int tn = dir ? (TT - 1 - sn) : sn;
        const float* gnext = gi + ((size_t)dir * TT + tn) * 1024;
        float g0n = gnext[r0], g1n = gnext[r1];
        int a0 = 0, a1 = 0, b0 = 0, b1 = 0;
        const v4i* h4 = (const v4i*)hq;
#define DOTC(c) { v4i h = h4[c];                                     \
        a0 = sdot4(wa##c.x, h.x, a0); a1 = sdot4(wa##c.y, h.y, a1);  \
        a0 = sdot4(wa##c.z, h.z, a0); a1 = sdot4(wa##c.w, h.w, a1);  \
        b0 = sdot4(wb##c.x, h.x, b0); b1 = sdot4(wb##c.y, h.y, b1);  \
        b0 = sdot4(wb##c.z, h.z, b0); b1 = sdot4(wb##c.w, h.w, b1); }
        DOTC(0); DOTC(1); DOTC(2); DOTC(3); DOTC(4); DOTC(5);
        DOTC(6); DOTC(7); DOTC(8); DOTC(9); DOTC(10); DOTC(11);
#undef DOTC
        // LDS-resident cols 192..255 (h chunks 12..15).
#pragma unroll
        for (int cc = 0; cc < 4; ++cc) {
            v4i h = h4[12 + cc];
            v4i va = *(const v4i*)&wsl[cc][r0][0];
            v4i vb = *(const v4i*)&wsl[cc][r1][0];
            a0 = sdot4(va.x, h.x, a0); a1 = sdot4(va.y, h.y, a1);
            a0 = sdot4(va.z, h.z, a0); a1 = sdot4(va.w, h.w, a1);
            b0 = sdot4(vb.x, h.x, b0); b1 = sdot4(vb.y, h.y, b1);
            b0 = sdot4(vb.z, h.z, b0); b1 = sdot4(vb.w, h.w, b1);
        }
        pa[r0] = (float)(a0 + a1) * fs0 + bh0 + g0v;
        pa[r1] = (float)(b0 + b1) * fs1 + bh1 + g1v;
        lds_barrier();
        if (tid < 256) {
            float iv = sigf(pa[tid]);
            float fv = sigf(pa[256 + tid]);
            float gv = tanhfast(pa[512 + tid]);
            float ov = sigf(pa[768 + tid]);
            c_state = fv * c_state + iv * gv;
            float h = ov * tanhfast(c_state);
            comb[(size_t)t * EE + dir * 256 + tid] = h;  // store left in flight
            ((signed char*)hq)[tid] = (signed char)__float2int_rn(h * 127.f);
        }
        lds_barrier();
        g0v = g0n; g1v = g1n;
    }
}

// ---------------- K10: logits + softmax ----------------
__global__ __launch_bounds__(128) void k_out(const float* __restrict__ comb,
                                             const float* __restrict__ Wout,
                                             const float* __restrict__ bout,
                                             float* __restrict__ out) {
    int t = blockIdx.x;
    __shared__ __align__(16) float cl[EE];
    __shared__ float ll[NTAGS];
    __shared__ float mred, sred;
    for (int i = threadIdx.x; i < EE; i += 128) cl[i] = comb[(size_t)t * EE + i];
    __syncthreads();
    int e = threadIdx.x;
    if (e < NTAGS) {
        const float* wr = Wout + (size_t)e * EE;
        float a0 = 0.f, a1 = 0.f;
#pragma unroll 4
        for (int k = 0; k < EE; k += 2) {
            a0 += cl[k] * wr[k];
            a1 += cl[k + 1] * wr[k + 1];
        }
        ll[e] = a0 + a1 + bout[e];
    }
    __syncthreads();
    if (threadIdx.x == 0) {
        float m = ll[0];
        for (int i = 1; i < NTAGS; ++i) m = fmaxf(m, ll[i]);
        float ss = 0.f;
        for (int i = 0; i < NTAGS; ++i) ss += __expf(ll[i] - m);
        mred = m;
        sred = ss;
    }
    __syncthreads();
    if (e < NTAGS) out[t * NTAGS + e] = __expf(ll[e] - mred) / sred;
}

// ---------------- workspace layout (floats) ----------------
#define OFF_DOTS  ((size_t)0)
#define OFF_P     ((size_t)512)
#define OFF_MBAR  ((size_t)1024)
#define OFF_G     ((size_t)66560)
#define OFF_GIG   ((size_t)132096)   // [2][512][192]
#define OFF_HBUF  ((size_t)328704)   // [512][128]
#define OFF_X     ((size_t)394240)   // [512][512]
#define OFF_GIL   ((size_t)656384)   // [2][512][1024]
#define OFF_COMB  ((size_t)1704960)  // [512][512]

extern "C" void kernel_launch(void* const* d_in, const int* in_sizes, int n_in,
                              void* d_out, int out_size, void* d_ws, size_t ws_size,
                              hipStream_t stream) {
    const float* memory = (const float*)d_in[0];
    const float* u      = (const float*)d_in[1];
    const float* embed  = (const float*)d_in[2];
    const float* W_ff   = (const float*)d_in[3];
    const float* b_ff   = (const float*)d_in[4];
    const float* gWih_f = (const float*)d_in[5];
    const float* gWhh_f = (const float*)d_in[6];
    const float* gbih_f = (const float*)d_in[7];
    const float* gbhh_f = (const float*)d_in[8];
    const float* gWih_b = (const float*)d_in[9];
    const float* gWhh_b = (const float*)d_in[10];
    const float* gbih_b = (const float*)d_in[11];
    const float* gbhh_b = (const float*)d_in[12];
    const float* W_k    = (const float*)d_in[13];
    const float* b_k    = (const float*)d_in[14];
    const float* lWih_f = (const float*)d_in[15];
    const float* lWhh_f = (const float*)d_in[16];
    const float* lbih_f = (const float*)d_in[17];
    const float* lbhh_f = (const float*)d_in[18];
    const float* lWih_b = (const float*)d_in[19];
    const float* lWhh_b = (const float*)d_in[20];
    const float* lbih_b = (const float*)d_in[21];
    const float* lbhh_b = (const float*)d_in[22];
    const float* W_out  = (const float*)d_in[23];
    const float* b_out  = (const float*)d_in[24];
    float* out = (float*)d_out;
    float* ws = (float*)d_ws;

    float* dots = ws + OFF_DOTS;
    float* p    = ws + OFF_P;
    float* Mbar = ws + OFF_MBAR;
    float* G    = ws + OFF_G;
    float* giG  = ws + OFF_GIG;
    float* hbuf = ws + OFF_HBUF;
    float* x    = ws + OFF_X;
    float* giL  = ws + OFF_GIL;
    float* comb = ws + OFF_COMB;

    k_dots<<<MM, 256, 0, stream>>>(memory, u, dots);
    k_softmax_p<<<1, MM, 0, stream>>>(dots, p);
    k_wsum<<<128, 128, 0, stream>>>(memory, p, Mbar);
    k_G<<<TT, DD, 0, stream>>>(Mbar, u, W_ff, b_ff, G);
    k_gru_gi<<<TT, 384, 0, stream>>>(G, gWih_f, gbih_f, gWih_b, gbih_b, giG);
    k_gru_seq<<<2, 256, 0, stream>>>(gWhh_f, gbhh_f, gWhh_b, gbhh_b, giG, hbuf);
    k_x<<<TT, EE, 0, stream>>>(u, hbuf, W_k, b_k, embed, x);
    k_lstm_gi<<<dim3(64, 2), 1024, 0, stream>>>(x, lWih_f, lbih_f, lWih_b, lbih_b, giL);
    k_lstm_seq<<<2, 512, 0, stream>>>(lWhh_f, lbhh_f, lWhh_b, lbhh_b, giL, comb);
    k_out<<<TT, 128, 0, stream>>>(comb, W_out, b_out, out);
}

// Round 2
// 1331.758 us; speedup vs baseline: 1.0085x; 1.0085x over previous
//
#include <hip/hip_runtime.h>
#include <math.h>

#define TT 512
#define DD 128
#define MM 512
#define EE 512
#define NTAGS 74
#define GH 64
#define LH 256

typedef _Float16 half_t;
typedef _Float16 v2h __attribute__((ext_vector_type(2)));
typedef _Float16 v8h __attribute__((ext_vector_type(8)));
typedef _Float16 v16h __attribute__((ext_vector_type(16)));
typedef int v4i __attribute__((ext_vector_type(4)));

__device__ __forceinline__ float fdot2f(v2h a, v2h b, float c) {
#if __has_builtin(__builtin_amdgcn_fdot2)
    return __builtin_amdgcn_fdot2(a, b, c, false);
#else
    return c + (float)a[0] * (float)b[0] + (float)a[1] * (float)b[1];
#endif
}

__device__ __forceinline__ int sdot4(int a, int b, int c) {
#if __has_builtin(__builtin_amdgcn_sdot4)
    return __builtin_amdgcn_sdot4(a, b, c, false);
#else
    return c + ((a << 24) >> 24) * ((b << 24) >> 24)
             + ((a << 16) >> 24) * ((b << 16) >> 24)
             + ((a << 8) >> 24) * ((b << 8) >> 24)
             + (a >> 24) * (b >> 24);
#endif
}

__device__ __forceinline__ float sigf(float x) { return 1.f / (1.f + __expf(-x)); }
__device__ __forceinline__ float tanhfast(float x) { return 1.f - 2.f / (__expf(2.f * x) + 1.f); }

// LDS-only barrier: orders LDS traffic across the workgroup WITHOUT the
// vmcnt(0) drain that __syncthreads() emits. Global stores (h writeback)
// and prefetch loads stay in flight across it (guide T4; rule 18 fences).
__device__ __forceinline__ void lds_barrier() {
    __builtin_amdgcn_sched_barrier(0);
    asm volatile("s_waitcnt lgkmcnt(0)" ::: "memory");
    __builtin_amdgcn_s_barrier();
    __builtin_amdgcn_sched_barrier(0);
}

// Single-wave LDS fence: ds ops of one wave complete in order; we only need
// the lgkmcnt drain + a sched fence so later reads aren't hoisted (rule 18).
__device__ __forceinline__ void wave_lds_fence() {
    __builtin_amdgcn_sched_barrier(0);
    asm volatile("s_waitcnt lgkmcnt(0)" ::: "memory");
    __builtin_amdgcn_sched_barrier(0);
}

// 16 f32 -> v16h (SSA value, 8 VGPRs)
__device__ __forceinline__ v16h load16(const float* p) {
    float4 x0 = ((const float4*)p)[0];
    float4 x1 = ((const float4*)p)[1];
    float4 x2 = ((const float4*)p)[2];
    float4 x3 = ((const float4*)p)[3];
    v16h r;
    r[0] = (half_t)x0.x; r[1] = (half_t)x0.y; r[2] = (half_t)x0.z; r[3] = (half_t)x0.w;
    r[4] = (half_t)x1.x; r[5] = (half_t)x1.y; r[6] = (half_t)x1.z; r[7] = (half_t)x1.w;
    r[8] = (half_t)x2.x; r[9] = (half_t)x2.y; r[10] = (half_t)x2.z; r[11] = (half_t)x2.w;
    r[12] = (half_t)x3.x; r[13] = (half_t)x3.y; r[14] = (half_t)x3.z; r[15] = (half_t)x3.w;
    return r;
}

#define OPAQUE4(a, b, c, d) \
    asm volatile("" : "+v"(a), "+v"(b), "+v"(c), "+v"(d))

__device__ __forceinline__ void dot16(const v16h& w, const v8h& h0, const v8h& h1,
                                      float& x0, float& x1) {
    x0 = fdot2f(v2h{w[0], w[1]}, v2h{h0[0], h0[1]}, x0);
    x1 = fdot2f(v2h{w[2], w[3]}, v2h{h0[2], h0[3]}, x1);
    x0 = fdot2f(v2h{w[4], w[5]}, v2h{h0[4], h0[5]}, x0);
    x1 = fdot2f(v2h{w[6], w[7]}, v2h{h0[6], h0[7]}, x1);
    x0 = fdot2f(v2h{w[8], w[9]}, v2h{h1[0], h1[1]}, x0);
    x1 = fdot2f(v2h{w[10], w[11]}, v2h{h1[2], h1[3]}, x1);
    x0 = fdot2f(v2h{w[12], w[13]}, v2h{h1[4], h1[5]}, x0);
    x1 = fdot2f(v2h{w[14], w[15]}, v2h{h1[6], h1[7]}, x1);
}

__device__ __forceinline__ int pack4(int b0, int b1, int b2, int b3) {
    return (b0 & 0xff) | ((b1 & 0xff) << 8) | ((b2 & 0xff) << 16) | (b3 << 24);
}

// quantize 16 consecutive f32 weights -> 16 int8 packed in v4i
__device__ __forceinline__ v4i quant16(const float* p, float inv_s) {
    float4 x0 = ((const float4*)p)[0];
    float4 x1 = ((const float4*)p)[1];
    float4 x2 = ((const float4*)p)[2];
    float4 x3 = ((const float4*)p)[3];
    v4i r;
    r.x = pack4(__float2int_rn(x0.x * inv_s), __float2int_rn(x0.y * inv_s),
                __float2int_rn(x0.z * inv_s), __float2int_rn(x0.w * inv_s));
    r.y = pack4(__float2int_rn(x1.x * inv_s), __float2int_rn(x1.y * inv_s),
                __float2int_rn(x1.z * inv_s), __float2int_rn(x1.w * inv_s));
    r.z = pack4(__float2int_rn(x2.x * inv_s), __float2int_rn(x2.y * inv_s),
                __float2int_rn(x2.z * inv_s), __float2int_rn(x2.w * inv_s));
    r.w = pack4(__float2int_rn(x3.x * inv_s), __float2int_rn(x3.y * inv_s),
                __float2int_rn(x3.z * inv_s), __float2int_rn(x3.w * inv_s));
    return r;
}

__device__ __forceinline__ float rowmax128(const float* p) {
    float m = 0.f;
#pragma unroll 8
    for (int k = 0; k < 128; k += 4) {
        float4 a = *(const float4*)(p + k);
        m = fmaxf(m, fmaxf(fmaxf(fabsf(a.x), fabsf(a.y)), fmaxf(fabsf(a.z), fabsf(a.w))));
    }
    return m;
}

// ---------------- K1: dots[m] = <memory[m], u> ----------------
__global__ __launch_bounds__(256) void k_dots(const float* __restrict__ mem,
                                              const float* __restrict__ u,
                                              float* __restrict__ dots) {
    int m = blockIdx.x;
    const float4* m4 = (const float4*)(mem + (size_t)m * TT * DD);
    const float4* u4 = (const float4*)u;
    float acc = 0.f;
#pragma unroll 4
    for (int it = 0; it < (TT * DD / 4) / 256; ++it) {
        int i = it * 256 + threadIdx.x;
        float4 a = m4[i], b = u4[i];
        acc += a.x * b.x + a.y * b.y + a.z * b.z + a.w * b.w;
    }
    for (int off = 32; off; off >>= 1) acc += __shfl_down(acc, off, 64);
    __shared__ float red[4];
    int w = threadIdx.x >> 6, l = threadIdx.x & 63;
    if (l == 0) red[w] = acc;
    __syncthreads();
    if (threadIdx.x == 0) dots[m] = red[0] + red[1] + red[2] + red[3];
}

// ---------------- K2: p = softmax(dots) ----------------
__global__ __launch_bounds__(512) void k_softmax_p(const float* __restrict__ dots,
                                                   float* __restrict__ p) {
    int tid = threadIdx.x;
    float v = dots[tid];
    float mx = v;
    for (int off = 32; off; off >>= 1) mx = fmaxf(mx, __shfl_down(mx, off, 64));
    __shared__ float red[8];
    __shared__ float bm, bs;
    int w = tid >> 6, l = tid & 63;
    if (l == 0) red[w] = mx;
    __syncthreads();
    if (tid == 0) {
        float t = red[0];
        for (int i = 1; i < 8; ++i) t = fmaxf(t, red[i]);
        bm = t;
    }
    __syncthreads();
    float e = __expf(v - bm);
    float sm = e;
    for (int off = 32; off; off >>= 1) sm += __shfl_down(sm, off, 64);
    if (l == 0) red[w] = sm;
    __syncthreads();
    if (tid == 0) {
        float t = 0.f;
        for (int i = 0; i < 8; ++i) t += red[i];
        bs = t;
    }
    __syncthreads();
    p[tid] = e / bs;
}

// ---------------- K3: Mbar = sum_m p[m]*memory[m] ----------------
__global__ __launch_bounds__(128) void k_wsum(const float* __restrict__ mem,
                                              const float* __restrict__ p,
                                              float* __restrict__ Mbar) {
    __shared__ float pl[MM];
    for (int i = threadIdx.x; i < MM; i += 128) pl[i] = p[i];
    __syncthreads();
    int i4 = blockIdx.x * 128 + threadIdx.x;
    const float4* m4 = (const float4*)mem;
    float4 acc = {0.f, 0.f, 0.f, 0.f};
#pragma unroll 4
    for (int m = 0; m < MM; ++m) {
        float pm = pl[m];
        float4 a = m4[(size_t)m * (TT * DD / 4) + i4];
        acc.x += pm * a.x; acc.y += pm * a.y; acc.z += pm * a.z; acc.w += pm * a.w;
    }
    ((float4*)Mbar)[i4] = acc;
}

// ---------------- K4: G = Mbar@W1.T + u@W2.T + b_ff ----------------
__global__ __launch_bounds__(128) void k_G(const float* __restrict__ Mbar,
                                           const float* __restrict__ u,
                                           const float* __restrict__ Wff,
                                           const float* __restrict__ bff,
                                           float* __restrict__ G) {
    int t = blockIdx.x, d = threadIdx.x;
    __shared__ __align__(16) float Ml[DD], ul[DD];
    Ml[d] = Mbar[t * DD + d];
    ul[d] = u[t * DD + d];
    __syncthreads();
    const float* wr = Wff + (size_t)d * 2 * DD;
    float a0 = 0.f, a1 = 0.f;
#pragma unroll 4
    for (int k = 0; k < DD; ++k) {
        a0 += Ml[k] * wr[k];
        a1 += ul[k] * wr[DD + k];
    }
    G[t * DD + d] = a0 + a1 + bff[d];
}

// ---------------- K5: GRU input projections ----------------
__global__ __launch_bounds__(384) void k_gru_gi(const float* __restrict__ G,
                                                const float* __restrict__ Wf,
                                                const float* __restrict__ bf,
                                                const float* __restrict__ Wb,
                                                const float* __restrict__ bb,
                                                float* __restrict__ gi) {
    int t = blockIdx.x;
    __shared__ __align__(16) float Gl[DD];
    if (threadIdx.x < DD) Gl[threadIdx.x] = G[t * DD + threadIdx.x];
    __syncthreads();
    int r = threadIdx.x;
    const float* w;
    float b;
    float* o;
    if (r < 192) {
        w = Wf + (size_t)r * DD; b = bf[r]; o = gi + ((size_t)0 * TT + t) * 192 + r;
    } else {
        int rr = r - 192;
        w = Wb + (size_t)rr * DD; b = bb[rr]; o = gi + ((size_t)1 * TT + t) * 192 + rr;
    }
    float a0 = 0.f, a1 = 0.f;
#pragma unroll 4
    for (int k = 0; k < DD; k += 2) {
        a0 += Gl[k] * w[k];
        a1 += Gl[k + 1] * w[k + 1];
    }
    *o = a0 + a1 + b;
}

// ---------------- K6: sequential BiGRU, ONE WAVE per direction ----------------
// 64 lanes = 64 hidden units; lane u owns rows {u, 64+u, 128+u} of Whh
// (r/z/n gates), all 64 cols as 12 v16h in registers. h broadcast via a
// 128-B LDS array; single wave => lockstep, NO barrier at all — only a
// lgkmcnt fence between the h write and the next step's reads. gi loads
// prefetched one step ahead; hbuf stores left in flight.
__global__ __launch_bounds__(64) void k_gru_seq(const float* __restrict__ Whh_f,
                                                const float* __restrict__ bhh_f,
                                                const float* __restrict__ Whh_b,
                                                const float* __restrict__ bhh_b,
                                                const float* __restrict__ gi,
                                                float* __restrict__ hbuf) {
    int dir = blockIdx.x;
    int u = threadIdx.x;  // 0..63
    const float* Whh = dir ? Whh_b : Whh_f;
    const float* bhh = dir ? bhh_b : bhh_f;
    const float* wr_ = Whh + (size_t)u * 64;
    const float* wz_ = Whh + (size_t)(64 + u) * 64;
    const float* wn_ = Whh + (size_t)(128 + u) * 64;
    v16h wr0 = load16(wr_), wr1 = load16(wr_ + 16), wr2 = load16(wr_ + 32), wr3 = load16(wr_ + 48);
    v16h wz0 = load16(wz_), wz1 = load16(wz_ + 16), wz2 = load16(wz_ + 32), wz3 = load16(wz_ + 48);
    v16h wn0 = load16(wn_), wn1 = load16(wn_ + 16), wn2 = load16(wn_ + 32), wn3 = load16(wn_ + 48);
    OPAQUE4(wr0, wr1, wr2, wr3);
    OPAQUE4(wz0, wz1, wz2, wz3);
    OPAQUE4(wn0, wn1, wn2, wn3);
    float bh_r = bhh[u], bh_z = bhh[64 + u], bh_n = bhh[128 + u];

    __shared__ __align__(16) half_t hl[64];
    hl[u] = (half_t)0.f;
    float h = 0.f;
    // prologue: gi for step 0
    int t0 = dir ? (TT - 1) : 0;
    const float* g0p = gi + ((size_t)dir * TT + t0) * 192;
    float g_r = g0p[u], g_z = g0p[64 + u], g_n = g0p[128 + u];
    wave_lds_fence();

    for (int s = 0; s < TT; ++s) {
        int t = dir ? (TT - 1 - s) : s;
        int sn = (s + 1 < TT) ? (s + 1) : s;
        int tn = dir ? (TT - 1 - sn) : sn;
        const float* gb = gi + ((size_t)dir * TT + tn) * 192;
        float pn_r = gb[u], pn_z = gb[64 + u], pn_n = gb[128 + u];

        const v8h* hv = (const v8h*)hl;
        v8h h0 = hv[0], h1 = hv[1], h2 = hv[2], h3 = hv[3];
        v8h h4 = hv[4], h5 = hv[5], h6 = hv[6], h7 = hv[7];
        float ar0 = bh_r, ar1 = 0.f, az0 = bh_z, az1 = 0.f, an0 = bh_n, an1 = 0.f;
        dot16(wr0, h0, h1, ar0, ar1); dot16(wr1, h2, h3, ar0, ar1);
        dot16(wr2, h4, h5, ar0, ar1); dot16(wr3, h6, h7, ar0, ar1);
        dot16(wz0, h0, h1, az0, az1); dot16(wz1, h2, h3, az0, az1);
        dot16(wz2, h4, h5, az0, az1); dot16(wz3, h6, h7, az0, az1);
        dot16(wn0, h0, h1, an0, an1); dot16(wn1, h2, h3, an0, an1);
        dot16(wn2, h4, h5, an0, an1); dot16(wn3, h6, h7, an0, an1);

        float r = sigf(g_r + ar0 + ar1);
        float z = sigf(g_z + az0 + az1);
        float n = tanhfast(g_n + r * (an0 + an1));
        h = (1.f - z) * n + z * h;
        hbuf[t * DD + dir * 64 + u] = h;   // store left in flight
        hl[u] = (half_t)h;
        wave_lds_fence();
        g_r = pn_r; g_z = pn_z; g_n = pn_n;
    }
}

// ---------------- K7: x = embed + (u + h)@W_k.T + b_k ----------------
__global__ __launch_bounds__(512) void k_x(const float* __restrict__ u,
                                           const float* __restrict__ hbuf,
                                           const float* __restrict__ Wk,
                                           const float* __restrict__ bk,
                                           const float* __restrict__ embed,
                                           float* __restrict__ x) {
    int t = blockIdx.x, e = threadIdx.x;
    __shared__ __align__(16) float sl[DD];
    if (e < DD) sl[e] = u[t * DD + e] + hbuf[t * DD + e];
    __syncthreads();
    const float* wr = Wk + (size_t)e * DD;
    float a0 = 0.f, a1 = 0.f;
#pragma unroll 4
    for (int k = 0; k < DD; k += 2) {
        a0 += sl[k] * wr[k];
        a1 += sl[k + 1] * wr[k + 1];
    }
    x[t * EE + e] = embed[t * EE + e] + a0 + a1 + bk[e];
}

// ---------------- K8: LSTM input projections, 8 timesteps per block ----------------
__global__ __launch_bounds__(1024) void k_lstm_gi(const float* __restrict__ x,
                                                  const float* __restrict__ Wf,
                                                  const float* __restrict__ bf,
                                                  const float* __restrict__ Wb,
                                                  const float* __restrict__ bb,
                                                  float* __restrict__ gi) {
    int dir = blockIdx.y;
    int t0 = blockIdx.x * 8;
    __shared__ __align__(16) float xl[8 * EE];
    for (int i = threadIdx.x; i < 8 * EE; i += 1024) xl[i] = x[(size_t)t0 * EE + i];
    __syncthreads();
    int r = threadIdx.x;
    const float* W = dir ? Wb : Wf;
    const float* bi = dir ? bb : bf;
    const float* wr = W + (size_t)r * EE;
    float b = bi[r];
    float acc[8];
#pragma unroll
    for (int uu = 0; uu < 8; ++uu) acc[uu] = b;
    for (int k = 0; k < EE; k += 4) {
        float4 wv = *(const float4*)(wr + k);
#pragma unroll
        for (int uu = 0; uu < 8; ++uu) {
            float4 xv = *(const float4*)(&xl[uu * EE + k]);
            acc[uu] += wv.x * xv.x + wv.y * xv.y + wv.z * xv.z + wv.w * xv.w;
        }
    }
#pragma unroll
    for (int uu = 0; uu < 8; ++uu)
        gi[((size_t)dir * TT + (t0 + uu)) * 1024 + r] = acc[uu];
}

// ---------------- K9: sequential BiLSTM, one WG per direction ----------------
// 512 threads = 2 per hidden unit (pair in adjacent lanes). Each thread owns
// all 4 gate rows {u, 256+u, 512+u, 768+u} over its 128-col half, int8 in
// 32 v4i REGISTERS (occupancy irrelevant: 2 blocks total -> 256-VGPR budget
// via __launch_bounds__(512,2)). Per-row symmetric quant (full-row max via
// pair shfl -> scales identical to the old 70-KB-LDS version; int math
// bitwise-identical). h broadcast via 256-B double-buffered hq; pair-reduce
// via __shfl_xor(.,1) -> no pa round-trip, ONE lds_barrier per step.
__global__ __launch_bounds__(512, 2) void k_lstm_seq(const float* __restrict__ Whh_f,
                                                     const float* __restrict__ bhh_f,
                                                     const float* __restrict__ Whh_b,
                                                     const float* __restrict__ bhh_b,
                                                     const float* __restrict__ gi,
                                                     float* __restrict__ comb) {
    int dir = blockIdx.x;
    int tid = threadIdx.x;
    int u = tid >> 1;
    int half = tid & 1;
    const float* Whh = dir ? Whh_b : Whh_f;
    const float* bhh = dir ? bhh_b : bhh_f;

    __shared__ __align__(16) int hq[2][64];  // 2 x 256 int8 h buffers

    const float* ri = Whh + (size_t)u * 256 + half * 128;
    const float* rf = Whh + (size_t)(256 + u) * 256 + half * 128;
    const float* rg = Whh + (size_t)(512 + u) * 256 + half * 128;
    const float* ro = Whh + (size_t)(768 + u) * 256 + half * 128;

    // full-row abs-max via own-half max + pair shfl (same value as before)
    float mi = rowmax128(ri); mi = fmaxf(mi, __shfl_xor(mi, 1, 64));
    float mf = rowmax128(rf); mf = fmaxf(mf, __shfl_xor(mf, 1, 64));
    float mg = rowmax128(rg); mg = fmaxf(mg, __shfl_xor(mg, 1, 64));
    float mo = rowmax128(ro); mo = fmaxf(mo, __shfl_xor(mo, 1, 64));
    float inv_i = 127.f / mi, inv_f = 127.f / mf, inv_g = 127.f / mg, inv_o = 127.f / mo;
    float fs_i = mi / 16129.f, fs_f = mf / 16129.f, fs_g = mg / 16129.f, fs_o = mo / 16129.f;

#define DECLROW(P, ptr, inv)                                                      \
    v4i P##0 = quant16((ptr), (inv)),       P##1 = quant16((ptr) + 16, (inv)),    \
        P##2 = quant16((ptr) + 32, (inv)),  P##3 = quant16((ptr) + 48, (inv)),    \
        P##4 = quant16((ptr) + 64, (inv)),  P##5 = quant16((ptr) + 80, (inv)),    \
        P##6 = quant16((ptr) + 96, (inv)),  P##7 = quant16((ptr) + 112, (inv));   \
    OPAQUE4(P##0, P##1, P##2, P##3);                                              \
    OPAQUE4(P##4, P##5, P##6, P##7)

    DECLROW(wi, ri, inv_i);
    DECLROW(wf, rf, inv_f);
    DECLROW(wg, rg, inv_g);
    DECLROW(wo, ro, inv_o);
#undef DECLROW

    float bh_i = bhh[u], bh_f = bhh[256 + u], bh_g = bhh[512 + u], bh_o = bhh[768 + u];
    if (tid < 64) hq[0][tid] = 0;
    float c_state = 0.f;
    // prologue: gi for step 0 (both pair threads load redundantly; same addr)
    int tfirst = dir ? (TT - 1) : 0;
    const float* gp0 = gi + ((size_t)dir * TT + tfirst) * 1024;
    float g_i = gp0[u], g_f = gp0[256 + u], g_g = gp0[512 + u], g_o = gp0[768 + u];
    lds_barrier();

#define ROWD1(P, c, A0, A1)                                          \
    A0 = sdot4(P##c.x, hv##c.x, A0); A1 = sdot4(P##c.y, hv##c.y, A1); \
    A0 = sdot4(P##c.z, hv##c.z, A0); A1 = sdot4(P##c.w, hv##c.w, A1)
#define ROWDOT(P, A0, A1)                                                  \
    ROWD1(P, 0, A0, A1); ROWD1(P, 1, A0, A1); ROWD1(P, 2, A0, A1);         \
    ROWD1(P, 3, A0, A1); ROWD1(P, 4, A0, A1); ROWD1(P, 5, A0, A1);         \
    ROWD1(P, 6, A0, A1); ROWD1(P, 7, A0, A1)

    for (int s = 0; s < TT; ++s) {
        int t = dir ? (TT - 1 - s) : s;
        // prefetch gi for step s+1 (clamped; consumed next iteration)
        int sn = (s + 1 < TT) ? (s + 1) : s;
        int tn = dir ? (TT - 1 - sn) : sn;
        const float* gb = gi + ((size_t)dir * TT + tn) * 1024;
        float pn_i = gb[u], pn_f = gb[256 + u], pn_g = gb[512 + u], pn_o = gb[768 + u];

        const v4i* hb = (const v4i*)&hq[s & 1][half * 32];
        v4i hv0 = hb[0], hv1 = hb[1], hv2 = hb[2], hv3 = hb[3];
        v4i hv4 = hb[4], hv5 = hb[5], hv6 = hb[6], hv7 = hb[7];
        int ai0 = 0, ai1 = 0, af0 = 0, af1 = 0, ag0 = 0, ag1 = 0, ao0 = 0, ao1 = 0;
        ROWDOT(wi, ai0, ai1);
        ROWDOT(wf, af0, af1);
        ROWDOT(wg, ag0, ag1);
        ROWDOT(wo, ao0, ao1);
        int ai = ai0 + ai1; ai += __shfl_xor(ai, 1, 64);
        int af = af0 + af1; af += __shfl_xor(af, 1, 64);
        int ag = ag0 + ag1; ag += __shfl_xor(ag, 1, 64);
        int ao = ao0 + ao1; ao += __shfl_xor(ao, 1, 64);

        float iv = sigf((float)ai * fs_i + bh_i + g_i);
        float fv = sigf((float)af * fs_f + bh_f + g_f);
        float gv = tanhfast((float)ag * fs_g + bh_g + g_g);
        float ov = sigf((float)ao * fs_o + bh_o + g_o);
        c_state = fv * c_state + iv * gv;
        float hval = ov * tanhfast(c_state);
        if (half == 0) {
            comb[(size_t)t * EE + dir * 256 + u] = hval;  // store left in flight
            ((signed char*)hq[(s + 1) & 1])[u] = (signed char)__float2int_rn(hval * 127.f);
        }
        lds_barrier();
        g_i = pn_i; g_f = pn_f; g_g = pn_g; g_o = pn_o;
    }
#undef ROWDOT
#undef ROWD1
}

// ---------------- K10: logits + softmax ----------------
__global__ __launch_bounds__(128) void k_out(const float* __restrict__ comb,
                                             const float* __restrict__ Wout,
                                             const float* __restrict__ bout,
                                             float* __restrict__ out) {
    int t = blockIdx.x;
    __shared__ __align__(16) float cl[EE];
    __shared__ float ll[NTAGS];
    __shared__ float mred, sred;
    for (int i = threadIdx.x; i < EE; i += 128) cl[i] = comb[(size_t)t * EE + i];
    __syncthreads();
    int e = threadIdx.x;
    if (e < NTAGS) {
        const float* wr = Wout + (size_t)e * EE;
        float a0 = 0.f, a1 = 0.f;
#pragma unroll 4
        for (int k = 0; k < EE; k += 2) {
            a0 += cl[k] * wr[k];
            a1 += cl[k + 1] * wr[k + 1];
        }
        ll[e] = a0 + a1 + bout[e];
    }
    __syncthreads();
    if (threadIdx.x == 0) {
        float m = ll[0];
        for (int i = 1; i < NTAGS; ++i) m = fmaxf(m, ll[i]);
        float ss = 0.f;
        for (int i = 0; i < NTAGS; ++i) ss += __expf(ll[i] - m);
        mred = m;
        sred = ss;
    }
    __syncthreads();
    if (e < NTAGS) out[t * NTAGS + e] = __expf(ll[e] - mred) / sred;
}

// ---------------- workspace layout (floats) ----------------
#define OFF_DOTS  ((size_t)0)
#define OFF_P     ((size_t)512)
#define OFF_MBAR  ((size_t)1024)
#define OFF_G     ((size_t)66560)
#define OFF_GIG   ((size_t)132096)   // [2][512][192]
#define OFF_HBUF  ((size_t)328704)   // [512][128]
#define OFF_X     ((size_t)394240)   // [512][512]
#define OFF_GIL   ((size_t)656384)   // [2][512][1024]
#define OFF_COMB  ((size_t)1704960)  // [512][512]

extern "C" void kernel_launch(void* const* d_in, const int* in_sizes, int n_in,
                              void* d_out, int out_size, void* d_ws, size_t ws_size,
                              hipStream_t stream) {
    const float* memory = (const float*)d_in[0];
    const float* u      = (const float*)d_in[1];
    const float* embed  = (const float*)d_in[2];
    const float* W_ff   = (const float*)d_in[3];
    const float* b_ff   = (const float*)d_in[4];
    const float* gWih_f = (const float*)d_in[5];
    const float* gWhh_f = (const float*)d_in[6];
    const float* gbih_f = (const float*)d_in[7];
    const float* gbhh_f = (const float*)d_in[8];
    const float* gWih_b = (const float*)d_in[9];
    const float* gWhh_b = (const float*)d_in[10];
    const float* gbih_b = (const float*)d_in[11];
    const float* gbhh_b = (const float*)d_in[12];
    const float* W_k    = (const float*)d_in[13];
    const float* b_k    = (const float*)d_in[14];
    const float* lWih_f = (const float*)d_in[15];
    const float* lWhh_f = (const float*)d_in[16];
    const float* lbih_f = (const float*)d_in[17];
    const float* lbhh_f = (const float*)d_in[18];
    const float* lWih_b = (const float*)d_in[19];
    const float* lWhh_b = (const float*)d_in[20];
    const float* lbih_b = (const float*)d_in[21];
    const float* lbhh_b = (const float*)d_in[22];
    const float* W_out  = (const float*)d_in[23];
    const float* b_out  = (const float*)d_in[24];
    float* out = (float*)d_out;
    float* ws = (float*)d_ws;

    float* dots = ws + OFF_DOTS;
    float* p    = ws + OFF_P;
    float* Mbar = ws + OFF_MBAR;
    float* G    = ws + OFF_G;
    float* giG  = ws + OFF_GIG;
    float* hbuf = ws + OFF_HBUF;
    float* x    = ws + OFF_X;
    float* giL  = ws + OFF_GIL;
    float* comb = ws + OFF_COMB;

    k_dots<<<MM, 256, 0, stream>>>(memory, u, dots);
    k_softmax_p<<<1, MM, 0, stream>>>(dots, p);
    k_wsum<<<128, 128, 0, stream>>>(memory, p, Mbar);
    k_G<<<TT, DD, 0, stream>>>(Mbar, u, W_ff, b_ff, G);
    k_gru_gi<<<TT, 384, 0, stream>>>(G, gWih_f, gbih_f, gWih_b, gbih_b, giG);
    k_gru_seq<<<2, 64, 0, stream>>>(gWhh_f, gbhh_f, gWhh_b, gbhh_b, giG, hbuf);
    k_x<<<TT, EE, 0, stream>>>(u, hbuf, W_k, b_k, embed, x);
    k_lstm_gi<<<dim3(64, 2), 1024, 0, stream>>>(x, lWih_f, lbih_f, lWih_b, lbih_b, giL);
    k_lstm_seq<<<2, 512, 0, stream>>>(lWhh_f, lbhh_f, lWhh_b, lbhh_b, giL, comb);
    k_out<<<TT, 128, 0, stream>>>(comb, W_out, b_out, out);
}